// Round 3
// baseline (352.774 us; speedup 1.0000x reference)
//
#include <hip/hip_runtime.h>
#include <hip/hip_bf16.h>
#include <stdint.h>

typedef unsigned short ushort_t;
typedef __attribute__((ext_vector_type(8))) short short8;   // 8 x bf16 (4 VGPRs) - MFMA A/B frag
typedef __attribute__((ext_vector_type(4))) short short4v;
typedef __attribute__((ext_vector_type(4))) float f32x4;    // MFMA C/D frag

// fp32 -> bf16 round-to-nearest-even (raw ushort)
__device__ inline ushort_t f2bf(float x) {
  uint32_t u = __float_as_uint(x);
  u += 0x7fffu + ((u >> 16) & 1u);
  return (ushort_t)(u >> 16);
}
__device__ inline float bfu2f(uint32_t h) { return __uint_as_float(h << 16); }

__device__ inline uint32_t pk2bf(float a, float b) {   // packed cvt, RNE
  __hip_bfloat162 h = __float22bfloat162_rn(make_float2(a, b));
  union { __hip_bfloat162 h2; uint32_t u; } cv; cv.h2 = h; return cv.u;
}

__device__ inline void gload_lds16(const void* g, void* l) {
  __builtin_amdgcn_global_load_lds((const __attribute__((address_space(1))) uint32_t*)g,
                                   (__attribute__((address_space(3))) uint32_t*)l, 16, 0, 0);
}

// ---------------------------------------------------------------------------
// K1: q = query @ W1^T + b1 ; k = key @ W2^T + b2   (fp32 in, bf16 out)
// C-tile 128x128, 4 waves each 64x64 (4x4 of 16x16x32 mfma), BK=32.
// v3: double-buffered staging (2x32KB), ONE barrier per iter, prefetch for
// it+1 issued right after the barrier -> vmcnt drain overlaps compute.
// Epilogue writes BOTH [n][d] and transposed [d][n] outputs.
// ---------------------------------------------------------------------------
__global__ __launch_bounds__(256, 2) void linear_kernel(
    const float* __restrict__ query, const float* __restrict__ key,
    const float* __restrict__ W1, const float* __restrict__ b1,
    const float* __restrict__ W2, const float* __restrict__ b2,
    ushort_t* __restrict__ q_bf, ushort_t* __restrict__ k_bf,
    ushort_t* __restrict__ qT, ushort_t* __restrict__ kT)
{
  __shared__ __attribute__((aligned(16))) char smraw[65536];
  float*    smF = (float*)smraw;     // buf c at c*8192 floats: A [0,4096), B [4096,8192)
  ushort_t* smU = (ushort_t*)smraw;  // epilogue overlay: [128][136] bf16

  int bx = blockIdx.x;
  int which = bx >> 9, r2 = bx & 511, ct = r2 & 3, rt = r2 >> 2;
  const float* X    = which ? key : query;   // [16384][512]
  const float* Wm   = which ? W2  : W1;      // [512][512] (row e is d-contiguous = B^T)
  const float* bias = which ? b2  : b1;
  ushort_t* OUT  = which ? k_bf : q_bf;
  ushort_t* OUTT = which ? kT   : qT;

  int t = threadIdx.x, w = t >> 6, lane = t & 63, g = lane >> 4, m = lane & 15;
  int wr = (w >> 1) * 64, wc = (w & 1) * 64;
  int sr = lane >> 3, sp = lane & 7, sc = sp ^ sr;  // staging row-in-slab, pos, src chunk

  f32x4 zero = {0.f, 0.f, 0.f, 0.f};
  f32x4 acc[4][4];
#pragma unroll
  for (int i = 0; i < 4; ++i)
#pragma unroll
    for (int j = 0; j < 4; ++j) acc[i][j] = zero;

  auto stage = [&](int bufsel, int d0) {
    float* dstb = smF + bufsel * 8192;
#pragma unroll
    for (int i = 0; i < 8; ++i) {
      int qi = w * 8 + i;
      const float* gsrc;
      float* ldst;
      if (qi < 16) {
        gsrc = X + (size_t)(rt * 128 + qi * 8 + sr) * 512 + d0 + sc * 4;
        ldst = dstb + qi * 256;
      } else {
        int s = qi - 16;
        gsrc = Wm + (size_t)(ct * 128 + s * 8 + sr) * 512 + d0 + sc * 4;
        ldst = dstb + 4096 + s * 256;
      }
      gload_lds16(gsrc, ldst);
    }
  };

  stage(0, 0);

  for (int it = 0; it < 16; ++it) {
    __syncthreads();                       // staging(cur) drained; prev frag reads done
    if (it + 1 < 16) stage((it + 1) & 1, (it + 1) * 32);
    const float* bF = smF + (it & 1) * 8192;

    short8 a4[4], b4[4];
#pragma unroll
    for (int i = 0; i < 4; ++i) {
      int row = wr + 16 * i + m, r8 = row & 7;
      int base = (row >> 3) * 256 + r8 * 32;
      f32x4 lo = *(const f32x4*)&bF[base + (((2 * g)     ^ r8) * 4)];
      f32x4 hi = *(const f32x4*)&bF[base + (((2 * g + 1) ^ r8) * 4)];
      union { uint32_t u[4]; short8 s; } fr;
      fr.u[0] = pk2bf(lo[0], lo[1]); fr.u[1] = pk2bf(lo[2], lo[3]);
      fr.u[2] = pk2bf(hi[0], hi[1]); fr.u[3] = pk2bf(hi[2], hi[3]);
      a4[i] = fr.s;
    }
#pragma unroll
    for (int j = 0; j < 4; ++j) {
      int row = wc + 16 * j + m, r8 = row & 7;
      int base = 4096 + (row >> 3) * 256 + r8 * 32;
      f32x4 lo = *(const f32x4*)&bF[base + (((2 * g)     ^ r8) * 4)];
      f32x4 hi = *(const f32x4*)&bF[base + (((2 * g + 1) ^ r8) * 4)];
      union { uint32_t u[4]; short8 s; } fr;
      fr.u[0] = pk2bf(lo[0], lo[1]); fr.u[1] = pk2bf(lo[2], lo[3]);
      fr.u[2] = pk2bf(hi[0], hi[1]); fr.u[3] = pk2bf(hi[2], hi[3]);
      b4[j] = fr.s;
    }
#pragma unroll
    for (int i = 0; i < 4; ++i)
#pragma unroll
      for (int j = 0; j < 4; ++j)
        acc[i][j] = __builtin_amdgcn_mfma_f32_16x16x32_bf16(a4[i], b4[j], acc[i][j], 0, 0, 0);
  }
  __syncthreads();                         // last frag reads done before epilogue overwrite

  float bw[4];
#pragma unroll
  for (int j = 0; j < 4; ++j) bw[j] = bias[ct * 128 + wc + 16 * j + m];

  // pass 1: [row][col] -> coalesced [n][d] stores
#pragma unroll
  for (int j = 0; j < 4; ++j)
#pragma unroll
    for (int i = 0; i < 4; ++i) {
      f32x4 c4 = acc[i][j];
#pragma unroll
      for (int rr = 0; rr < 4; ++rr)
        smU[(wr + 16 * i + 4 * g + rr) * 136 + wc + 16 * j + m] = f2bf(c4[rr] + bw[j]);
    }
  __syncthreads();
  {
    int row = t >> 1, half = t & 1;
    size_t gb = (size_t)(rt * 128 + row) * 512 + ct * 128 + half * 64;
#pragma unroll
    for (int i = 0; i < 8; ++i)
      *(short8*)(OUT + gb + i * 8) = *(const short8*)&smU[row * 136 + half * 64 + i * 8];
  }
  __syncthreads();

  // pass 2: transposed [col][row] -> [d][n] stores
#pragma unroll
  for (int j = 0; j < 4; ++j)
#pragma unroll
    for (int i = 0; i < 4; ++i) {
      f32x4 c4 = acc[i][j];
      short4v tv;
#pragma unroll
      for (int rr = 0; rr < 4; ++rr) tv[rr] = (short)f2bf(c4[rr] + bw[j]);
      *(short4v*)&smU[(wc + 16 * j + m) * 136 + wr + 16 * i + 4 * g] = tv;
    }
  __syncthreads();
  {
    int cC = t >> 1, half = t & 1;
    size_t b_ = (size_t)(rt >> 4);
    size_t gb = b_ * (512 * 2048) + (size_t)(ct * 128 + cC) * 2048
              + (size_t)(rt & 15) * 128 + half * 64;
#pragma unroll
    for (int i = 0; i < 8; ++i)
      *(short8*)(OUTT + gb + i * 8) = *(const short8*)&smU[cC * 136 + half * 64 + i * 8];
  }
}

// ---------------------------------------------------------------------------
// K3: attention. v3: 4 waves x 32 q-rows (2 q-groups per wave) -> every
// K-frag / V-frag ds_read feeds 2 MFMAs: per-CU LDS read traffic halved
// vs v2 (which measured at 92% of the ds_read_b128 pipe ceiling).
// Grid 256 = 16 (b,att) groups x 16 mtiles (128 rows/block). 1 block/CU,
// 128 KB dbuf LDS, one barrier per iter. ~470 unified VGPR+AGPR, 1 wave/SIMD.
// ---------------------------------------------------------------------------
__global__ __launch_bounds__(256, 1) void attn_kernel(
    const ushort_t* __restrict__ qb, const ushort_t* __restrict__ kb_,
    const ushort_t* __restrict__ qT, const ushort_t* __restrict__ kT,
    float* __restrict__ out)
{
  extern __shared__ ushort_t sm[];        // 131072 B: buf c at c*32768 (K 16K ushorts, VT 16K)
  const float CEXP = 1.4426950408889634f / 22.62741699796952f; // log2(e)/sqrt(512)

  int bx = blockIdx.x;
  int group = bx & 15, mtile = bx >> 4;
  int b = group >> 1, att = group & 1;
  const ushort_t* Qp = (att ? kb_ : qb) + (size_t)b * (2048 * 512);
  const ushort_t* Kp = (att ? qb  : kb_) + (size_t)b * (2048 * 512);
  const ushort_t* Vt = (att ? kT  : qT)  + (size_t)b * (512 * 2048);

  int t = threadIdx.x, w = t >> 6, lane = t & 63, g = lane >> 4, m = lane & 15;
  int qrow0 = mtile * 128 + w * 32 + m;              // group 0: rows +0..15
  int qrow1 = qrow0 + 16;                            // group 1: rows +16..31
  int sw8  = ((g ^ ((m >> 1) & 3)) * 8);             // swizzled read chunk offset (ushorts)
  int srow = lane >> 2;                              // staging row within slab
  int soff = ((lane & 3) ^ ((lane >> 3) & 3)) * 8;   // staging source col offset (ushorts)

  // Q fragments (MFMA B-operand for S^T = K * Q^T): 2 groups x 16 ksteps x 16B
  short8 qf0[16], qf1[16];
#pragma unroll
  for (int ks = 0; ks < 16; ++ks) {
    qf0[ks] = *(const short8*)(Qp + (size_t)qrow0 * 512 + ks * 32 + g * 8);
    qf1[ks] = *(const short8*)(Qp + (size_t)qrow1 * 512 + ks * 32 + g * 8);
  }

  f32x4 zero = {0.f, 0.f, 0.f, 0.f};
  f32x4 acc0[32], acc1[32];
#pragma unroll
  for (int dt = 0; dt < 32; ++dt) { acc0[dt] = zero; acc1[dt] = zero; }
  float l0 = 0.f, l1 = 0.f;

  auto stage = [&](int buf, int kb) {
    ushort_t* base = sm + buf * 32768;
    const int kbase = kb * 32;
#pragma unroll
    for (int i = 0; i < 8; ++i) {          // K tile: 32 slabs of 1KB (16 keys x 32d), 8/wave
      int qi = w * 8 + i, ks = qi >> 1, tt2 = qi & 1;
      const ushort_t* gsrc = Kp + (size_t)(kbase + tt2 * 16 + srow) * 512 + ks * 32 + soff;
      gload_lds16(gsrc, base + ks * 1024 + tt2 * 512);
    }
#pragma unroll
    for (int i = 0; i < 8; ++i) {          // V^T tile: 32 slabs (16 d-rows x 32 keys), 8/wave
      int qi = w * 8 + i;
      const ushort_t* gsrc = Vt + (size_t)(qi * 16 + srow) * 2048 + kbase + soff;
      gload_lds16(gsrc, base + 16384 + qi * 512);
    }
  };

  // softmax + C-frag -> B-frag (P^T) relayout for one q-group
  auto softpack = [&](const f32x4& Ta, const f32x4& Tb, float& l) -> short8 {
    uint32_t h[8];
#pragma unroll
    for (int r = 0; r < 4; ++r) {
      float e0 = __builtin_amdgcn_exp2f(Ta[r] * CEXP);
      float e1 = __builtin_amdgcn_exp2f(Tb[r] * CEXP);
      h[r]     = f2bf(e0);
      h[4 + r] = f2bf(e1);
      l += bfu2f(h[r]) + bfu2f(h[4 + r]);
    }
    int dw0 = (int)(h[0] | (h[1] << 16));
    int dw1 = (int)(h[2] | (h[3] << 16));
    int dw2 = (int)(h[4] | (h[5] << 16));
    int dw3 = (int)(h[6] | (h[7] << 16));
    int sA = ((2 * g) & 3) * 16 + m, sB = sA + 16;
    int A0 = __shfl(dw0, sA, 64), A1 = __shfl(dw1, sA, 64);
    int A2 = __shfl(dw2, sA, 64), A3 = __shfl(dw3, sA, 64);
    int B0 = __shfl(dw0, sB, 64), B1 = __shfl(dw1, sB, 64);
    int B2 = __shfl(dw2, sB, 64), B3 = __shfl(dw3, sB, 64);
    bool hi = (g >= 2);
    union { int i4[4]; short8 s; } pu;
    pu.i4[0] = hi ? A2 : A0; pu.i4[1] = hi ? A3 : A1;
    pu.i4[2] = hi ? B2 : B0; pu.i4[3] = hi ? B3 : B1;
    return pu.s;
  };

  stage(0, 0);

  for (int kb = 0; kb < 64; ++kb) {
    int cur = kb & 1;
    __syncthreads();                       // staging(cur) complete; prev reads of 1-cur done
    if (kb + 1 < 64) stage(1 - cur, kb + 1);
    const ushort_t* base = sm + cur * 32768;

    // S^T: T0/T1 = keys 0-15/16-31 x group0 ; T2/T3 = same keys x group1
    f32x4 T0 = zero, T1 = zero, T2 = zero, T3 = zero;
#pragma unroll
    for (int ks = 0; ks < 16; ++ks) {
      short8 k0 = *(const short8*)&base[ks * 1024 +       m * 32 + sw8];
      short8 k1 = *(const short8*)&base[ks * 1024 + 512 + m * 32 + sw8];
      T0 = __builtin_amdgcn_mfma_f32_16x16x32_bf16(k0, qf0[ks], T0, 0, 0, 0);
      T1 = __builtin_amdgcn_mfma_f32_16x16x32_bf16(k1, qf0[ks], T1, 0, 0, 0);
      T2 = __builtin_amdgcn_mfma_f32_16x16x32_bf16(k0, qf1[ks], T2, 0, 0, 0);
      T3 = __builtin_amdgcn_mfma_f32_16x16x32_bf16(k1, qf1[ks], T3, 0, 0, 0);
    }

    short8 pfrag0 = softpack(T0, T1, l0);
    short8 pfrag1 = softpack(T2, T3, l1);

    // O^T += V^T * P^T : each V-frag read feeds BOTH groups' MFMAs
#pragma unroll
    for (int dt = 0; dt < 32; ++dt) {
      short8 vf = *(const short8*)&base[16384 + dt * 512 + m * 32 + sw8];
      acc0[dt] = __builtin_amdgcn_mfma_f32_16x16x32_bf16(vf, pfrag0, acc0[dt], 0, 0, 0);
      acc1[dt] = __builtin_amdgcn_mfma_f32_16x16x32_bf16(vf, pfrag1, acc1[dt], 0, 0, 0);
    }
  }

  // row-sum reduce (col m lives in lanes m, m+16, m+32, m+48) and store
  l0 += __shfl_xor(l0, 16, 64); l0 += __shfl_xor(l0, 32, 64);
  l1 += __shfl_xor(l1, 16, 64); l1 += __shfl_xor(l1, 32, 64);
  float inv0 = 1.0f / l0, inv1 = 1.0f / l1;
  size_t orow0 = (size_t)b * 4096 + (size_t)att * 2048 + qrow0;
  float* ob0 = out + orow0 * 512;
  float* ob1 = ob0 + 16 * 512;
#pragma unroll
  for (int dt = 0; dt < 32; ++dt) {
    f32x4 v0 = acc0[dt] * inv0;
    f32x4 v1 = acc1[dt] * inv1;
    *(f32x4*)(ob0 + dt * 16 + g * 4) = v0;
    *(f32x4*)(ob1 + dt * 16 + g * 4) = v1;
  }
}

// ---------------------------------------------------------------------------
extern "C" void kernel_launch(void* const* d_in, const int* in_sizes, int n_in,
                              void* d_out, int out_size, void* d_ws, size_t ws_size,
                              hipStream_t stream) {
  const float* query = (const float*)d_in[0];
  const float* key   = (const float*)d_in[1];
  const float* W1    = (const float*)d_in[2];
  const float* b1    = (const float*)d_in[3];
  const float* W2    = (const float*)d_in[4];
  const float* b2    = (const float*)d_in[5];
  float* out = (float*)d_out;

  ushort_t* ws   = (ushort_t*)d_ws;        // needs 64 MB
  ushort_t* q_bf = ws;                     // [8][2048][512] bf16
  ushort_t* k_bf = ws + 8388608;
  ushort_t* qT   = ws + 16777216;          // [8][512][2048] bf16
  ushort_t* kT   = ws + 25165824;

  (void)hipFuncSetAttribute((const void*)attn_kernel,
                            hipFuncAttributeMaxDynamicSharedMemorySize, 131072);

  linear_kernel<<<1024, 256, 0, stream>>>(query, key, W1, b1, W2, b2,
                                          q_bf, k_bf, qT, kT);
  attn_kernel<<<256, 256, 131072, stream>>>(q_bf, k_bf, qT, kT, out);
}